// Round 4
// baseline (474.134 us; speedup 1.0000x reference)
//
#include <hip/hip_runtime.h>

// LePEAttention without softmax:  out = Q (K^T V) * (2*SCALE)
// q,k,v: (T=4, B=2, C=256, H=56, W=56) fp32. Windows: 2 of 56x28 (N=1568),
// heads=8, d=32. 128 problems: p = ((t*2+b)*2+win)*8+head.
//
// Kernel 1 (kv): 256 blocks, one per HALF-problem (784 positions = 7 chunks
//   of 112). Double-buffered global_load_lds staging with counted
//   s_waitcnt vmcnt(7) + raw s_barrier (prefetch stays in flight across the
//   barrier). Permuted-slot LDS layout (conflict-free b128 reads, proven R3).
//   Register accumulator across all 7 chunks; one 4KB partial per block.
// Kernel 2 (qm): 256 blocks, one per half-problem. M = SCALE2*(part0+part1);
//   each thread computes 4 consecutive positions with float4 Q loads/stores.

#define HW 3136
#define WDIM 56
#define NPROB 128
#define PSPLIT 112
#define SCALE2 0.35355339059327373f   // 2 * 32^-0.5

typedef const __attribute__((address_space(1))) void gas_void;
typedef __attribute__((address_space(3))) void las_void;
typedef float v2f __attribute__((ext_vector_type(2)));

// ---------------- Kernel 1: half-problem K^T V ------------------------------
__global__ __launch_bounds__(256) void kv_kernel(const float* __restrict__ K,
                                                 const float* __restrict__ V,
                                                 float* __restrict__ Mpart) {
    __shared__ float lds[2 * 7168];          // two 28,672B chunk buffers
    float* bufA = lds;
    float* bufB = lds + 7168;

    const int g = blockIdx.x;                // 256 blocks
    const int p = g >> 1;                    // problem
    const int h = g & 1;                     // half: positions [h*784, h*784+784)
    const int head = p & 7;
    const int win  = (p >> 3) & 1;
    const int b    = (p >> 4) & 1;
    const int t    = p >> 5;

    const size_t base = (size_t)((t * 2 + b) * 256 + head * 32) * HW;
    const float* __restrict__ Kb = K + base;
    const float* __restrict__ Vb = V + base;

    const int tid = threadIdx.x;
    const int l   = tid & 63;
    const int w   = tid >> 6;

    // per-lane chunk-0 global sources; chunk c adds c*112 positions = c*224 floats
    const float* srcs[7];
    #pragma unroll
    for (int i = 0; i < 7; ++i) {
        const int q    = (w * 7 + i) * 64 + l;
        const int isv  = q >= 896 ? 1 : 0;   // wave-uniform (896 = 14*64)
        const int r    = q - isv * 896;
        const int pq   = r >> 5;             // position quad 0..27
        const int slot = r & 31;             // permuted channel slot
        const int ch   = ((slot & 7) << 2) + (slot >> 3);
        const int n    = h * 7 * PSPLIT + pq * 4;   // first-chunk position
        const int y    = n / 28;
        const int x    = n - y * 28;
        srcs[i] = (isv ? Vb : Kb) + (size_t)ch * HW + y * WDIM + win * 28 + x;
    }

    auto stage = [&](int c, float* buf) {
        #pragma unroll
        for (int i = 0; i < 7; ++i)
            __builtin_amdgcn_global_load_lds((gas_void*)(srcs[i] + c * 224),
                                             (las_void*)&buf[(w * 7 + i) * 256],
                                             16, 0, 0);
    };

    const int gg = l >> 3;       // dd0 = 4*gg
    const int e  = l & 7;        // de0 = 4*e
    v2f acc2[4][4] = {};         // persists across all 7 chunks

    auto compute = [&](const float* __restrict__ buf) {
        #pragma unroll
        for (int j = 0; j < 7; ++j) {
            const int rowb = (7 * w + j) * 128;   // pq row of this wave
            float4 ka[4], va[4];
            #pragma unroll
            for (int i = 0; i < 4; ++i) {
                ka[i] = *(const float4*)&buf[rowb + (gg + 8 * i) * 4];
                va[i] = *(const float4*)&buf[3584 + rowb + (e + 8 * i) * 4];
            }
            #pragma unroll
            for (int i = 0; i < 4; ++i) {
                const v2f ka_lo = {ka[i].x, ka[i].y};
                const v2f ka_hi = {ka[i].z, ka[i].w};
                #pragma unroll
                for (int jj = 0; jj < 4; ++jj) {
                    const v2f va_lo = {va[jj].x, va[jj].y};
                    const v2f va_hi = {va[jj].z, va[jj].w};
                    acc2[i][jj] += ka_lo * va_lo;   // v_pk_fma_f32
                    acc2[i][jj] += ka_hi * va_hi;
                }
            }
        }
    };

    stage(0, bufA);
    stage(1, bufB);
    #pragma unroll
    for (int c = 0; c < 7; ++c) {
        __builtin_amdgcn_sched_barrier(0);
        if (c < 6) asm volatile("s_waitcnt vmcnt(7)" ::: "memory");  // chunk c done
        else       asm volatile("s_waitcnt vmcnt(0)" ::: "memory");
        __builtin_amdgcn_sched_barrier(0);
        __builtin_amdgcn_s_barrier();          // all waves' chunk c resident
        __builtin_amdgcn_sched_barrier(0);
        compute((c & 1) ? bufB : bufA);
        __builtin_amdgcn_sched_barrier(0);
        __builtin_amdgcn_s_barrier();          // all waves done reading buf[c&1]
        __builtin_amdgcn_sched_barrier(0);
        if (c + 2 <= 6) stage(c + 2, (c & 1) ? bufB : bufA);
    }

    // reduce the 4 wave copies (overlay lds[0..4095]; vmcnt already 0)
    const int dd0 = gg * 4;
    const int de0 = e * 4;
    #pragma unroll
    for (int i = 0; i < 4; ++i)
        #pragma unroll
        for (int jj = 0; jj < 4; ++jj)
            lds[w * 1024 + (dd0 + i) * 32 + (de0 + jj)] = acc2[i][jj].x + acc2[i][jj].y;
    __syncthreads();

    const float4 r0 = *(const float4*)&lds[tid * 4];
    const float4 r1 = *(const float4*)&lds[1024 + tid * 4];
    const float4 r2 = *(const float4*)&lds[2048 + tid * 4];
    const float4 r3 = *(const float4*)&lds[3072 + tid * 4];
    float4 o;
    o.x = r0.x + r1.x + r2.x + r3.x;
    o.y = r0.y + r1.y + r2.y + r3.y;
    o.z = r0.z + r1.z + r2.z + r3.z;
    o.w = r0.w + r1.w + r2.w + r3.w;
    *(float4*)&Mpart[(size_t)g * 1024 + tid * 4] = o;
}

// ---------------- Kernel 2: out = Q * (SCALE2 * (part0+part1)) --------------
__global__ __launch_bounds__(256) void qm_kernel(const float* __restrict__ Q,
                                                 const float* __restrict__ Mpart,
                                                 float* __restrict__ Out) {
    __shared__ float M[1024];
    const int g = blockIdx.x;                // 256 blocks
    const int p = g >> 1;
    const int h = g & 1;                     // half: position quads [h*196, h*196+196)
    const int tid = threadIdx.x;

    const float* mp = Mpart + (size_t)p * 2048 + tid * 4;
    const float4 a0 = *(const float4*)mp;
    const float4 a1 = *(const float4*)(mp + 1024);
    float4 sum;
    sum.x = (a0.x + a1.x) * SCALE2;
    sum.y = (a0.y + a1.y) * SCALE2;
    sum.z = (a0.z + a1.z) * SCALE2;
    sum.w = (a0.w + a1.w) * SCALE2;
    *(float4*)&M[tid * 4] = sum;
    __syncthreads();

    const int head = p & 7;
    const int win  = (p >> 3) & 1;
    const int b    = (p >> 4) & 1;
    const int t    = p >> 5;

    if (tid < 196) {
        const int qd = h * 196 + tid;        // position quad 0..391
        const int y  = qd / 7;
        const int x  = (qd - y * 7) * 4;
        const size_t base = (size_t)((t * 2 + b) * 256 + head * 32) * HW
                          + y * WDIM + win * 28 + x;
        const float* __restrict__ Qb = Q + base;
        float* __restrict__ Ob = Out + base;

        v2f accL[32] = {};   // positions {0,1} per output channel
        v2f accH[32] = {};   // positions {2,3}
        #pragma unroll 8
        for (int dd = 0; dd < 32; ++dd) {
            const float4 q4 = *(const float4*)&Qb[(size_t)dd * HW];
            const v2f qL = {q4.x, q4.y};
            const v2f qH = {q4.z, q4.w};
            #pragma unroll
            for (int de4 = 0; de4 < 8; ++de4) {
                const float4 m = *(const float4*)&M[dd * 32 + de4 * 4];  // broadcast
                accL[de4 * 4 + 0] += qL * m.x;  accH[de4 * 4 + 0] += qH * m.x;
                accL[de4 * 4 + 1] += qL * m.y;  accH[de4 * 4 + 1] += qH * m.y;
                accL[de4 * 4 + 2] += qL * m.z;  accH[de4 * 4 + 2] += qH * m.z;
                accL[de4 * 4 + 3] += qL * m.w;  accH[de4 * 4 + 3] += qH * m.w;
            }
        }
        #pragma unroll
        for (int de = 0; de < 32; ++de) {
            float4 o;
            o.x = accL[de].x; o.y = accL[de].y;
            o.z = accH[de].x; o.w = accH[de].y;
            *(float4*)&Ob[(size_t)de * HW] = o;
        }
    }
}

extern "C" void kernel_launch(void* const* d_in, const int* in_sizes, int n_in,
                              void* d_out, int out_size, void* d_ws, size_t ws_size,
                              hipStream_t stream) {
    const float* q = (const float*)d_in[0];
    const float* k = (const float*)d_in[1];
    const float* v = (const float*)d_in[2];
    // d_in[3] is v_lamda == 1 (ignored)
    float* out   = (float*)d_out;
    float* Mpart = (float*)d_ws;   // 256*1024 floats = 1 MB, fully written by kv

    kv_kernel<<<256, 256, 0, stream>>>(k, v, Mpart);
    qm_kernel<<<256, 256, 0, stream>>>(q, Mpart, out);
}

// Round 5
// 178.069 us; speedup vs baseline: 2.6626x; 2.6626x over previous
//
#include <hip/hip_runtime.h>

// LePEAttention without softmax:  out = Q (K^T V) * (2*SCALE)
// q,k,v: (T=4, B=2, C=256, H=56, W=56) fp32. Windows: 2 of 56x28 (N=1568),
// heads=8, d=32. 128 problems: p = ((t*2+b)*2+win)*8+head.
//
// Kernel 1 (kv): 256 blocks, one per HALF-problem (784 positions = 7 chunks
//   of 112). Double-buffered global_load_lds staging, counted vmcnt(7) +
//   raw s_barrier (prefetch stays in flight across barriers). Permuted-slot
//   LDS layout (conflict-free b128 reads). R4's spill storm (VGPR=256,
//   680MB scratch traffic) is fixed: no sched_barrier walls, u32 offsets
//   instead of 64-bit pointer array, wave-uniform K/V base (isv == w>=2).
// Kernel 2 (qm): unchanged from R4 (correct, loads deep enough).

#define HW 3136
#define WDIM 56
#define SCALE2 0.35355339059327373f   // 2 * 32^-0.5

typedef const __attribute__((address_space(1))) void gas_void;
typedef __attribute__((address_space(3))) void las_void;
typedef float v2f __attribute__((ext_vector_type(2)));

// ---------------- Kernel 1: half-problem K^T V ------------------------------
__global__ __launch_bounds__(256) void kv_kernel(const float* __restrict__ K,
                                                 const float* __restrict__ V,
                                                 float* __restrict__ Mpart) {
    __shared__ float lds[2 * 7168];          // two 28,672B chunk buffers

    const int g = blockIdx.x;                // 256 blocks
    const int p = g >> 1;                    // problem
    const int h = g & 1;                     // half: positions [h*784, h*784+784)
    const int head = p & 7;
    const int win  = (p >> 3) & 1;
    const int b    = (p >> 4) & 1;
    const int t    = p >> 5;

    const size_t base = (size_t)((t * 2 + b) * 256 + head * 32) * HW;

    const int tid = threadIdx.x;
    const int l   = tid & 63;
    const int w   = tid >> 6;

    // waves 0,1 stage K; waves 2,3 stage V (quad 896 = 14*64 boundary)
    const float* __restrict__ Tb = (w >= 2 ? V : K) + base;

    // per-lane chunk-0 source offsets (floats); chunk c adds c*224
    unsigned off[7];
    #pragma unroll
    for (int i = 0; i < 7; ++i) {
        const int q    = (w * 7 + i) * 64 + l;
        const int r    = q >= 896 ? q - 896 : q;
        const int pq   = r >> 5;             // position quad 0..27
        const int slot = r & 31;             // permuted channel slot
        const int ch   = ((slot & 7) << 2) + (slot >> 3);
        const int n    = h * 784 + pq * 4;   // first-chunk position
        const int y    = n / 28;
        const int x    = n - y * 28;
        off[i] = (unsigned)(ch * HW + y * WDIM + win * 28 + x);
    }

    float* bufA = lds;
    float* bufB = lds + 7168;

#define STAGE(c, buf) do {                                                     \
        _Pragma("unroll")                                                      \
        for (int i = 0; i < 7; ++i)                                            \
            __builtin_amdgcn_global_load_lds(                                  \
                (gas_void*)(Tb + off[i] + (c) * 224),                          \
                (las_void*)&(buf)[(w * 7 + i) * 256], 16, 0, 0);               \
    } while (0)

    STAGE(0, bufA);
    STAGE(1, bufB);

    const int gg = l >> 3;       // dd0 = 4*gg
    const int e  = l & 7;        // de0 = 4*e
    v2f acc2[4][4] = {};         // persists across all 7 chunks

    #pragma unroll
    for (int c = 0; c < 7; ++c) {
        if (c < 6) asm volatile("s_waitcnt vmcnt(7)" ::: "memory");  // chunk c resident (this wave)
        else       asm volatile("s_waitcnt vmcnt(0)" ::: "memory");
        __builtin_amdgcn_s_barrier();        // chunk c resident (all waves)

        const float* __restrict__ buf = (c & 1) ? bufB : bufA;
        #pragma unroll
        for (int j = 0; j < 7; ++j) {
            const int rowb = (7 * w + j) * 128;   // this wave's pq rows
            float4 ka[4], va[4];
            #pragma unroll
            for (int i = 0; i < 4; ++i) {
                ka[i] = *(const float4*)&buf[rowb + (gg + 8 * i) * 4];
                va[i] = *(const float4*)&buf[3584 + rowb + (e + 8 * i) * 4];
            }
            #pragma unroll
            for (int i = 0; i < 4; ++i) {
                const v2f ka_lo = {ka[i].x, ka[i].y};
                const v2f ka_hi = {ka[i].z, ka[i].w};
                #pragma unroll
                for (int jj = 0; jj < 4; ++jj) {
                    const v2f va_lo = {va[jj].x, va[jj].y};
                    const v2f va_hi = {va[jj].z, va[jj].w};
                    acc2[i][jj] += ka_lo * va_lo;   // v_pk_fma_f32
                    acc2[i][jj] += ka_hi * va_hi;
                }
            }
        }

        __builtin_amdgcn_s_barrier();        // all waves done reading buf
        if (c < 5) STAGE(c + 2, (c & 1) ? bufB : bufA);
    }
#undef STAGE

    // reduce the 4 wave copies (overlay lds[0..4095]; DMA fully drained)
    const int dd0 = gg * 4;
    const int de0 = e * 4;
    #pragma unroll
    for (int i = 0; i < 4; ++i)
        #pragma unroll
        for (int jj = 0; jj < 4; ++jj)
            lds[w * 1024 + (dd0 + i) * 32 + (de0 + jj)] = acc2[i][jj].x + acc2[i][jj].y;
    __syncthreads();

    const float4 r0 = *(const float4*)&lds[tid * 4];
    const float4 r1 = *(const float4*)&lds[1024 + tid * 4];
    const float4 r2 = *(const float4*)&lds[2048 + tid * 4];
    const float4 r3 = *(const float4*)&lds[3072 + tid * 4];
    float4 o;
    o.x = r0.x + r1.x + r2.x + r3.x;
    o.y = r0.y + r1.y + r2.y + r3.y;
    o.z = r0.z + r1.z + r2.z + r3.z;
    o.w = r0.w + r1.w + r2.w + r3.w;
    *(float4*)&Mpart[(size_t)g * 1024 + tid * 4] = o;
}

// ---------------- Kernel 2: out = Q * (SCALE2 * (part0+part1)) --------------
__global__ __launch_bounds__(256) void qm_kernel(const float* __restrict__ Q,
                                                 const float* __restrict__ Mpart,
                                                 float* __restrict__ Out) {
    __shared__ float M[1024];
    const int g = blockIdx.x;                // 256 blocks
    const int p = g >> 1;
    const int h = g & 1;                     // half: position quads [h*196, h*196+196)
    const int tid = threadIdx.x;

    const float* mp = Mpart + (size_t)p * 2048 + tid * 4;
    const float4 a0 = *(const float4*)mp;
    const float4 a1 = *(const float4*)(mp + 1024);
    float4 sum;
    sum.x = (a0.x + a1.x) * SCALE2;
    sum.y = (a0.y + a1.y) * SCALE2;
    sum.z = (a0.z + a1.z) * SCALE2;
    sum.w = (a0.w + a1.w) * SCALE2;
    *(float4*)&M[tid * 4] = sum;
    __syncthreads();

    const int head = p & 7;
    const int win  = (p >> 3) & 1;
    const int b    = (p >> 4) & 1;
    const int t    = p >> 5;

    if (tid < 196) {
        const int qd = h * 196 + tid;        // position quad 0..391
        const int y  = qd / 7;
        const int x  = (qd - y * 7) * 4;
        const size_t base = (size_t)((t * 2 + b) * 256 + head * 32) * HW
                          + y * WDIM + win * 28 + x;
        const float* __restrict__ Qb = Q + base;
        float* __restrict__ Ob = Out + base;

        v2f accL[32] = {};   // positions {0,1} per output channel
        v2f accH[32] = {};   // positions {2,3}
        #pragma unroll 8
        for (int dd = 0; dd < 32; ++dd) {
            const float4 q4 = *(const float4*)&Qb[(size_t)dd * HW];
            const v2f qL = {q4.x, q4.y};
            const v2f qH = {q4.z, q4.w};
            #pragma unroll
            for (int de4 = 0; de4 < 8; ++de4) {
                const float4 m = *(const float4*)&M[dd * 32 + de4 * 4];  // broadcast
                accL[de4 * 4 + 0] += qL * m.x;  accH[de4 * 4 + 0] += qH * m.x;
                accL[de4 * 4 + 1] += qL * m.y;  accH[de4 * 4 + 1] += qH * m.y;
                accL[de4 * 4 + 2] += qL * m.z;  accH[de4 * 4 + 2] += qH * m.z;
                accL[de4 * 4 + 3] += qL * m.w;  accH[de4 * 4 + 3] += qH * m.w;
            }
        }
        #pragma unroll
        for (int de = 0; de < 32; ++de) {
            float4 o;
            o.x = accL[de].x; o.y = accL[de].y;
            o.z = accH[de].x; o.w = accH[de].y;
            *(float4*)&Ob[(size_t)de * HW] = o;
        }
    }
}

extern "C" void kernel_launch(void* const* d_in, const int* in_sizes, int n_in,
                              void* d_out, int out_size, void* d_ws, size_t ws_size,
                              hipStream_t stream) {
    const float* q = (const float*)d_in[0];
    const float* k = (const float*)d_in[1];
    const float* v = (const float*)d_in[2];
    // d_in[3] is v_lamda == 1 (ignored)
    float* out   = (float*)d_out;
    float* Mpart = (float*)d_ws;   // 256*1024 floats = 1 MB, fully written by kv

    kv_kernel<<<256, 256, 0, stream>>>(k, v, Mpart);
    qm_kernel<<<256, 256, 0, stream>>>(q, Mpart, out);
}

// Round 6
// 127.826 us; speedup vs baseline: 3.7092x; 1.3931x over previous
//
#include <hip/hip_runtime.h>

// LePEAttention without softmax:  out = Q (K^T V) * (2*SCALE)
// q,k,v: (T=4, B=2, C=256, H=56, W=56) fp32. Windows: 2 of 56x28 (N=1568),
// heads=8, d=32. 128 problems: p = ((t*2+b)*2+win)*8+head.
//
// Kernel 1 (kv): Mpart[p][s] = K_s^T V_s over 112-position split s (14 splits).
//   R3 structure (1792 blocks, single-shot global_load_lds stage, 28KB LDS,
//   5 blocks/CU -> inter-block TLP is the pipeline) + permuted-slot LDS
//   layout (conflict-free b128) + pk_fma. NEW: __launch_bounds__(256,4)
//   caps VGPR at 128 -- R4/R5's deep-pipeline variant hit the 256-VGPR cap
//   and spilled ~66MB/iter to scratch at 1 block/CU (107us); reverted.
// Kernel 2 (qm): M = SCALE2 * sum_s Mpart[p][s];  out = Q * M.
//   896 blocks. Q loads issued BEFORE the partial-sum phase (T14 issue-early)
//   so HBM latency hides under the Mpart reduction + barrier.

#define HW 3136
#define WDIM 56
#define SPLIT 14
#define PSPLIT 112
#define SCALE2 0.35355339059327373f   // 2 * 32^-0.5

typedef const __attribute__((address_space(1))) void gas_void;
typedef __attribute__((address_space(3))) void las_void;
typedef float v2f __attribute__((ext_vector_type(2)));

// ---------------- Kernel 1: partial K^T V ----------------------------------
__global__ __launch_bounds__(256, 4) void kv_kernel(const float* __restrict__ K,
                                                    const float* __restrict__ V,
                                                    float* __restrict__ Mpart) {
    // [tensor:2][pq:28][slot:32] 16B-quads, fp32 -> 28672 B (4 blocks/CU w/ VGPR cap)
    __shared__ float lds[2 * 32 * PSPLIT];

    const int blk = blockIdx.x;
    const int p   = blk / SPLIT;
    const int s   = blk - p * SPLIT;
    const int head = p & 7;
    const int win  = (p >> 3) & 1;
    const int b    = (p >> 4) & 1;
    const int t    = p >> 5;

    const size_t base = (size_t)((t * 2 + b) * 256 + head * 32) * HW;
    const float* __restrict__ Kb = K + base;
    const float* __restrict__ Vb = V + base;

    const int tid = threadIdx.x;
    const int l   = tid & 63;
    const int w   = tid >> 6;

    // ---- stage: 1792 16B-quads. Linear LDS dest (wave-uniform base + lane*16);
    // per-lane GLOBAL source realizes the permuted-slot layout.
    #pragma unroll
    for (int i = 0; i < 7; ++i) {
        const int q    = (w * 7 + i) * 64 + l;
        const int isv  = q >= 896 ? 1 : 0;    // wave-uniform (896 = 14*64)
        const int r    = q - isv * 896;
        const int pq   = r >> 5;              // position quad 0..27
        const int slot = r & 31;              // permuted channel slot
        const int ch   = ((slot & 7) << 2) + (slot >> 3);
        const int n    = s * PSPLIT + pq * 4; // global position, 4-aligned
        const int y    = n / 28;
        const int x    = n - y * 28;
        const float* src = (isv ? Vb : Kb)
                         + (size_t)ch * HW + y * WDIM + win * 28 + x;  // 16B-aligned
        float* dst = &lds[(w * 7 + i) * 256];   // wave-uniform
        __builtin_amdgcn_global_load_lds((gas_void*)src, (las_void*)dst, 16, 0, 0);
    }
    __syncthreads();   // compiler emits s_waitcnt vmcnt(0) before barrier

    // ---- rank-1 accumulation: lane owns 4x4 tile of the 32x32 output.
    const int gg = l >> 3;       // dd0 = 4*gg
    const int e  = l & 7;        // de0 = 4*e

    v2f acc2[4][4] = {};
    #pragma unroll
    for (int j = 0; j < 7; ++j) {
        const int rowb = (7 * w + j) * 128;   // this wave's pq rows
        float4 ka[4], va[4];
        #pragma unroll
        for (int i = 0; i < 4; ++i) {
            // granule class = gg (ka) / e (va) mod 8 -> conflict-free
            ka[i] = *(const float4*)&lds[rowb + (gg + 8 * i) * 4];
            va[i] = *(const float4*)&lds[3584 + rowb + (e + 8 * i) * 4];
        }
        #pragma unroll
        for (int i = 0; i < 4; ++i) {
            const v2f ka_lo = {ka[i].x, ka[i].y};
            const v2f ka_hi = {ka[i].z, ka[i].w};
            #pragma unroll
            for (int jj = 0; jj < 4; ++jj) {
                const v2f va_lo = {va[jj].x, va[jj].y};
                const v2f va_hi = {va[jj].z, va[jj].w};
                acc2[i][jj] += ka_lo * va_lo;   // v_pk_fma_f32
                acc2[i][jj] += ka_hi * va_hi;
            }
        }
    }
    __syncthreads();

    // ---- reduce the 4 wave copies (overlay lds[0..4095])
    const int dd0 = gg * 4;
    const int de0 = e * 4;
    #pragma unroll
    for (int i = 0; i < 4; ++i)
        #pragma unroll
        for (int jj = 0; jj < 4; ++jj)
            lds[w * 1024 + (dd0 + i) * 32 + (de0 + jj)] = acc2[i][jj].x + acc2[i][jj].y;
    __syncthreads();

    const float4 r0 = *(const float4*)&lds[tid * 4];
    const float4 r1 = *(const float4*)&lds[1024 + tid * 4];
    const float4 r2 = *(const float4*)&lds[2048 + tid * 4];
    const float4 r3 = *(const float4*)&lds[3072 + tid * 4];
    float4 o;
    o.x = r0.x + r1.x + r2.x + r3.x;
    o.y = r0.y + r1.y + r2.y + r3.y;
    o.z = r0.z + r1.z + r2.z + r3.z;
    o.w = r0.w + r1.w + r2.w + r3.w;
    *(float4*)&Mpart[(size_t)blk * 1024 + tid * 4] = o;
}

// ---------------- Kernel 2: out = Q * (SCALE2 * sum_s Mpart) ----------------
__global__ __launch_bounds__(256, 4) void qm_kernel(const float* __restrict__ Q,
                                                    const float* __restrict__ Mpart,
                                                    float* __restrict__ Out) {
    __shared__ float M[1024];
    const int blk = blockIdx.x;              // 896 blocks
    const int p   = blk / 7;
    const int c   = blk - p * 7;
    const int tid = threadIdx.x;

    const int head = p & 7;
    const int win  = (p >> 3) & 1;
    const int b    = (p >> 4) & 1;
    const int t    = p >> 5;

    // ---- issue Q loads EARLY (T14): latency hides under the Mpart reduction
    const float* __restrict__ Qb = nullptr;
    float*       __restrict__ Ob = nullptr;
    float qv[32];
    if (tid < 224) {
        const int n = c * 224 + tid;          // 7 blocks x 224 = 1568
        const int y = n / 28;
        const int x = n - y * 28;
        const size_t base = (size_t)((t * 2 + b) * 256 + head * 32) * HW
                          + y * WDIM + win * 28 + x;
        Qb = Q + base;
        Ob = Out + base;
        #pragma unroll
        for (int dd = 0; dd < 32; ++dd)
            qv[dd] = Qb[(size_t)dd * HW];
    }

    // ---- sum the 14 partials; fold in the scale
    const float* mp = Mpart + (size_t)p * SPLIT * 1024 + tid * 4;
    v2f s0 = {0.f, 0.f}, s1 = {0.f, 0.f};
    #pragma unroll
    for (int s = 0; s < SPLIT; ++s) {
        const float4 v = *(const float4*)&mp[s * 1024];
        const v2f vlo = {v.x, v.y};
        const v2f vhi = {v.z, v.w};
        s0 += vlo; s1 += vhi;
    }
    float4 sum;
    sum.x = s0.x * SCALE2; sum.y = s0.y * SCALE2;
    sum.z = s1.x * SCALE2; sum.w = s1.y * SCALE2;
    *(float4*)&M[tid * 4] = sum;
    __syncthreads();

    if (tid < 224) {
        v2f acc2[16] = {};   // acc2[g*2+h] covers de = g*4 + h*2 + {0,1}
        #pragma unroll 8
        for (int dd = 0; dd < 32; ++dd) {
            const v2f qq = {qv[dd], qv[dd]};
            #pragma unroll
            for (int g4 = 0; g4 < 8; ++g4) {
                const float4 m = *(const float4*)&M[dd * 32 + g4 * 4];  // broadcast b128
                const v2f mlo = {m.x, m.y};
                const v2f mhi = {m.z, m.w};
                acc2[g4 * 2 + 0] += qq * mlo;   // v_pk_fma_f32
                acc2[g4 * 2 + 1] += qq * mhi;
            }
        }
        #pragma unroll
        for (int g4 = 0; g4 < 8; ++g4) {
            Ob[(size_t)(g4 * 4 + 0) * HW] = acc2[g4 * 2 + 0].x;
            Ob[(size_t)(g4 * 4 + 1) * HW] = acc2[g4 * 2 + 0].y;
            Ob[(size_t)(g4 * 4 + 2) * HW] = acc2[g4 * 2 + 1].x;
            Ob[(size_t)(g4 * 4 + 3) * HW] = acc2[g4 * 2 + 1].y;
        }
    }
}

extern "C" void kernel_launch(void* const* d_in, const int* in_sizes, int n_in,
                              void* d_out, int out_size, void* d_ws, size_t ws_size,
                              hipStream_t stream) {
    const float* q = (const float*)d_in[0];
    const float* k = (const float*)d_in[1];
    const float* v = (const float*)d_in[2];
    // d_in[3] is v_lamda == 1 (ignored)
    float* out   = (float*)d_out;
    float* Mpart = (float*)d_ws;   // 128*14*1024 floats = 7.34 MB, fully written by kv

    kv_kernel<<<128 * SPLIT, 256, 0, stream>>>(k, v, Mpart);
    qm_kernel<<<128 * 7, 256, 0, stream>>>(q, Mpart, out);
}